// Round 2
// baseline (282.376 us; speedup 1.0000x reference)
//
#include <hip/hip_runtime.h>
#include <math.h>

#define N_RES 1024
#define N_ATOMS 37
#define ATOM_CA 1
#define NBATCH 256
#define SLICES 2              // partial rows per batch (2 residues per thread)
#define NSUM 18
// Mask is binary ({0,1}) => m^2 == m, so the m^2-weighted moments equal the
// m-weighted ones. sums layout per partial row:
// 0: M = sum m
// 1-3: Sp = sum m*p          4-6: St = sum m*t
// 7: Qp = sum m*|p|^2        8: Qt = sum m*|t|^2
// 9-17: Cpt[i][j] = sum m*p_i*t_j
//
// Workspace layout: float partials[512][18] (36864 B), then uint ticket (4 B).

// 12-byte, 4-aligned coordinate triple -> single global_load_dwordx3 per
// tensor per residue (3 VMEM/lane/residue incl. mask = structural minimum
// for this 444B-strided layout).
struct F3 { float x, y, z; };

// Fused kernel: 512 blocks x 256 threads. Block blk covers batch blk>>1,
// residues (blk&1)*512 + tid and +256 (2 residues/thread -> 8 scattered
// loads in flight per thread for latency hiding; half the waves of the
// 1-residue/thread version -> half the shuffle-reduce tail).
// Last block to finish runs the fp64 QCP finish for all 256 batches
// (one batch per thread), eliminating the second dispatch.
__global__ __launch_bounds__(256) void rmsd_fused_kernel(
    const float* __restrict__ pred, const float* __restrict__ truec,
    const float* __restrict__ mask, float* __restrict__ partials,
    unsigned int* __restrict__ ticket, float* __restrict__ out)
{
    const int blk   = blockIdx.x;          // 0..511
    const int b     = blk >> 1;            // batch
    const int slice = blk & 1;
    const int tid   = threadIdx.x;
    const int n0    = slice * 512 + tid;   // first residue; second is n0+256

    const size_t resStride = (size_t)N_ATOMS * 3;
    const size_t r0 = (size_t)b * N_RES + n0;
    const size_t r1 = r0 + 256;

    // Issue all six memory ops up front (independent -> all in flight).
    const F3 P0 = *reinterpret_cast<const F3*>(pred  + r0 * resStride + ATOM_CA * 3);
    const F3 T0 = *reinterpret_cast<const F3*>(truec + r0 * resStride + ATOM_CA * 3);
    const F3 P1 = *reinterpret_cast<const F3*>(pred  + r1 * resStride + ATOM_CA * 3);
    const F3 T1 = *reinterpret_cast<const F3*>(truec + r1 * resStride + ATOM_CA * 3);
    const float m0 = mask[r0 * N_ATOMS + ATOM_CA];
    const float m1 = mask[r1 * N_ATOMS + ATOM_CA];

    float acc[NSUM];
    acc[0] = m0 + m1;
    acc[1] = m0 * P0.x + m1 * P1.x;
    acc[2] = m0 * P0.y + m1 * P1.y;
    acc[3] = m0 * P0.z + m1 * P1.z;
    acc[4] = m0 * T0.x + m1 * T1.x;
    acc[5] = m0 * T0.y + m1 * T1.y;
    acc[6] = m0 * T0.z + m1 * T1.z;
    acc[7] = m0 * (P0.x*P0.x + P0.y*P0.y + P0.z*P0.z)
           + m1 * (P1.x*P1.x + P1.y*P1.y + P1.z*P1.z);
    acc[8] = m0 * (T0.x*T0.x + T0.y*T0.y + T0.z*T0.z)
           + m1 * (T1.x*T1.x + T1.y*T1.y + T1.z*T1.z);
    acc[9]  = m0 * P0.x * T0.x + m1 * P1.x * T1.x;
    acc[10] = m0 * P0.x * T0.y + m1 * P1.x * T1.y;
    acc[11] = m0 * P0.x * T0.z + m1 * P1.x * T1.z;
    acc[12] = m0 * P0.y * T0.x + m1 * P1.y * T1.x;
    acc[13] = m0 * P0.y * T0.y + m1 * P1.y * T1.y;
    acc[14] = m0 * P0.y * T0.z + m1 * P1.y * T1.z;
    acc[15] = m0 * P0.z * T0.x + m1 * P1.z * T1.x;
    acc[16] = m0 * P0.z * T0.y + m1 * P1.z * T1.y;
    acc[17] = m0 * P0.z * T0.z + m1 * P1.z * T1.z;

    // wave(64) shuffle reduce
#pragma unroll
    for (int i = 0; i < NSUM; ++i) {
        float v = acc[i];
#pragma unroll
        for (int off = 32; off > 0; off >>= 1) v += __shfl_down(v, off, 64);
        acc[i] = v;
    }

    __shared__ float partial[4][NSUM];
    const int wave = tid >> 6, lane = tid & 63;
    if (lane == 0) {
#pragma unroll
        for (int i = 0; i < NSUM; ++i) partial[wave][i] = acc[i];
    }
    __syncthreads();
    if (tid < NSUM) {
        partials[(size_t)blk * NSUM + tid] =
            partial[0][tid] + partial[1][tid] + partial[2][tid] + partial[3][tid];
    }

    // ---- last-block-done handoff (device-scope, XCD-safe) ----
    __threadfence();              // release: partials stores -> device scope
    __syncthreads();              // writers' fences happen-before tid0's atomic
    __shared__ bool amLast;
    if (tid == 0)
        amLast = (atomicAdd(ticket, 1u) == (unsigned)(gridDim.x - 1));
    __syncthreads();
    if (!amLast) return;
    __threadfence();              // acquire: see all blocks' partials

    // ---- finish: thread b = batch b. Theobald QCP, fp64, register-only
    // (any dynamically-indexed array would be demoted to scratch). ----
    {
        const int bb = tid;
        double s[NSUM];
#pragma unroll
        for (int i = 0; i < NSUM; ++i) s[i] = 0.0;
#pragma unroll
        for (int k = 0; k < SLICES; ++k) {
            const float* row = partials + ((size_t)bb * SLICES + k) * NSUM;
#pragma unroll
            for (int i = 0; i < NSUM; ++i) s[i] += (double)row[i];
        }

        const double M   = s[0];
        const double Mep = M + 1e-8;
        const double Sp0 = s[1], Sp1 = s[2], Sp2 = s[3];
        const double St0 = s[4], St1 = s[5], St2 = s[6];
        const double pc0 = Sp0 / Mep, pc1 = Sp1 / Mep, pc2 = Sp2 / Mep;
        const double tc0 = St0 / Mep, tc1 = St1 / Mep, tc2 = St2 / Mep;
        const double Qp = s[7], Qt = s[8];

        // H[i][j] = sum m (p-pc)_i (t-tc)_j
        const double Sxx = s[9]  - pc0 * St0 - tc0 * Sp0 + pc0 * tc0 * M;
        const double Sxy = s[10] - pc0 * St1 - tc1 * Sp0 + pc0 * tc1 * M;
        const double Sxz = s[11] - pc0 * St2 - tc2 * Sp0 + pc0 * tc2 * M;
        const double Syx = s[12] - pc1 * St0 - tc0 * Sp1 + pc1 * tc0 * M;
        const double Syy = s[13] - pc1 * St1 - tc1 * Sp1 + pc1 * tc1 * M;
        const double Syz = s[14] - pc1 * St2 - tc2 * Sp1 + pc1 * tc2 * M;
        const double Szx = s[15] - pc2 * St0 - tc0 * Sp2 + pc2 * tc0 * M;
        const double Szy = s[16] - pc2 * St1 - tc1 * Sp2 + pc2 * tc1 * M;
        const double Szz = s[17] - pc2 * St2 - tc2 * Sp2 + pc2 * tc2 * M;

        const double Qpc = Qp - 2.0*(pc0*Sp0 + pc1*Sp1 + pc2*Sp2)
                         + (pc0*pc0 + pc1*pc1 + pc2*pc2) * M;
        const double Qtc = Qt - 2.0*(tc0*St0 + tc1*St1 + tc2*St2)
                         + (tc0*tc0 + tc1*tc1 + tc2*tc2) * M;

        // ---- QCP characteristic quartic: x^4 + C2 x^2 + C1 x + C0 ----
        const double Sxx2 = Sxx*Sxx, Syy2 = Syy*Syy, Szz2 = Szz*Szz;
        const double Sxy2 = Sxy*Sxy, Syz2 = Syz*Syz, Sxz2 = Sxz*Sxz;
        const double Syx2 = Syx*Syx, Szy2 = Szy*Szy, Szx2 = Szx*Szx;

        const double SyzSzymSyySzz2 = 2.0*(Syz*Szy - Syy*Szz);
        const double Sxx2Syy2Szz2Syz2Szy2 = Syy2 + Szz2 - Sxx2 + Syz2 + Szy2;

        const double C2 = -2.0*(Sxx2 + Syy2 + Szz2 + Sxy2 + Syx2 + Sxz2 + Szx2 + Syz2 + Szy2);
        const double C1 = 8.0*(Sxx*Syz*Szy + Syy*Szx*Sxz + Szz*Sxy*Syx
                             - Sxx*Syy*Szz - Syz*Szx*Sxy - Szy*Syx*Sxz);

        const double SxzpSzx = Sxz + Szx;
        const double SyzpSzy = Syz + Szy;
        const double SxypSyx = Sxy + Syx;
        const double SyzmSzy = Syz - Szy;
        const double SxzmSzx = Sxz - Szx;
        const double SxymSyx = Sxy - Syx;
        const double SxxpSyy = Sxx + Syy;
        const double SxxmSyy = Sxx - Syy;
        const double Sxy2Sxz2Syx2Szx2 = Sxy2 + Sxz2 - Syx2 - Szx2;

        const double C0 =
            Sxy2Sxz2Syx2Szx2 * Sxy2Sxz2Syx2Szx2
          + (Sxx2Syy2Szz2Syz2Szy2 + SyzSzymSyySzz2) * (Sxx2Syy2Szz2Syz2Szy2 - SyzSzymSyySzz2)
          + (-(SxzpSzx)*(SyzmSzy) + (SxymSyx)*(SxxmSyy - Szz)) *
            (-(SxzmSzx)*(SyzpSzy) + (SxymSyx)*(SxxmSyy + Szz))
          + (-(SxzpSzx)*(SyzpSzy) - (SxypSyx)*(SxxpSyy - Szz)) *
            (-(SxzmSzx)*(SyzmSzy) - (SxypSyx)*(SxxpSyy + Szz))
          + ( (SxypSyx)*(SyzpSzy) + (SxzpSzx)*(SxxmSyy + Szz)) *
            (-(SxymSyx)*(SyzmSzy) + (SxzpSzx)*(SxxpSyy + Szz))
          + ( (SxypSyx)*(SyzmSzy) + (SxzmSzx)*(SxxmSyy - Szz)) *
            (-(SxymSyx)*(SyzpSzy) + (SxzmSzx)*(SxxpSyy - Szz));

        // Newton from above: lambda0 = (Qpc+Qtc)/2 >= lambda_max.
        double lam = 0.5 * (Qpc + Qtc);
#pragma unroll
        for (int it = 0; it < 16; ++it) {
            const double x2 = lam * lam;
            const double bq = (x2 + C2) * lam;
            const double aq = bq + C1;
            const double den = 2.0 * x2 * lam + bq + aq;
            const double num = aq * lam + C0;
            const double d = (fabs(den) > 1e-300) ? (num / den) : 0.0;
            lam -= d;
        }

        double D = Qpc + Qtc - 2.0 * lam;
        if (D < 0.0) D = 0.0;
        float rmsd = (float)sqrt(D / Mep);

        // mean over 256 batches
#pragma unroll
        for (int off = 32; off > 0; off >>= 1) rmsd += __shfl_down(rmsd, off, 64);
        __shared__ float part[4];
        if ((tid & 63) == 0) part[tid >> 6] = rmsd;
        __syncthreads();
        if (tid == 0)
            out[0] = (part[0] + part[1] + part[2] + part[3]) * (1.0f / (float)NBATCH);
    }
}

extern "C" void kernel_launch(void* const* d_in, const int* in_sizes, int n_in,
                              void* d_out, int out_size, void* d_ws, size_t ws_size,
                              hipStream_t stream) {
    const float* pred  = (const float*)d_in[0];
    const float* truec = (const float*)d_in[1];
    const float* mask  = (const float*)d_in[2];
    float* out = (float*)d_out;
    float* partials = (float*)d_ws;                       // 512*18 floats = 36864 B
    unsigned int* ticket = (unsigned int*)((char*)d_ws + 512 * NSUM * sizeof(float));

    // Graph-capturable (memset node); guarantees ticket==0 on every replay.
    hipMemsetAsync(ticket, 0, sizeof(unsigned int), stream);
    rmsd_fused_kernel<<<NBATCH * SLICES, 256, 0, stream>>>(
        pred, truec, mask, partials, ticket, out);
}